// Round 1
// baseline (1459.138 us; speedup 1.0000x reference)
//
#include <hip/hip_runtime.h>
#include <hip/hip_fp16.h>

// MoE top-2, T=16384 tokens, D=1024, H=2048, E=8. All inputs fp32.
// Pipeline: router(top2+x->f16) -> scan -> build lists -> transpose-cvt weights
// -> grouped GEMM1 (gate+up fused, SiLU) -> grouped GEMM2 (down, atomicAdd out).
// Internal compute in f16 MFMA (16x16x32), fp32 accumulate. Router kept fp32.

#define T_TOK 16384
#define EMB_D 1024
#define HID_D 2048
#define NEXP  8
#define LIST_CAP (2 * T_TOK + 256)

typedef _Float16 f16x8 __attribute__((ext_vector_type(8)));
typedef float    f32x4 __attribute__((ext_vector_type(4)));

// async global->LDS, 16B per lane, lane i lands at ldsbase + i*16B
#define GLD16(gp, lp)                                                          \
  __builtin_amdgcn_global_load_lds(                                            \
      (__attribute__((address_space(1))) void*)(void*)(gp),                    \
      (__attribute__((address_space(3))) void*)(lp), 16, 0, 0)

// ---------------------------------------------------------------- router ----
__global__ __launch_bounds__(256) void router_kernel(
    const float* __restrict__ x, const float* __restrict__ rw,
    _Float16* __restrict__ xh, int* __restrict__ top_idx,
    float2* __restrict__ top_w, int* __restrict__ counts) {
  int wave = threadIdx.x >> 6, lane = threadIdx.x & 63;
  int t = blockIdx.x * 4 + wave;              // one wave per token
  const float* xr = x + (size_t)t * EMB_D;
  int d0 = lane * 16;

  float xv[16];
#pragma unroll
  for (int j = 0; j < 4; j++) {
    float4 v = *(const float4*)(xr + d0 + j * 4);
    xv[j * 4 + 0] = v.x; xv[j * 4 + 1] = v.y;
    xv[j * 4 + 2] = v.z; xv[j * 4 + 3] = v.w;
  }
  // fused fp32 -> f16 conversion of x (RNE via v_cvt_f16_f32)
  _Float16 hx[16];
#pragma unroll
  for (int j = 0; j < 16; j++) hx[j] = (_Float16)xv[j];
  *(f16x8*)(xh + (size_t)t * EMB_D + d0)     = *(f16x8*)(hx);
  *(f16x8*)(xh + (size_t)t * EMB_D + d0 + 8) = *(f16x8*)(hx + 8);

  // logits in fp32 (selection must be exact-ish)
  float acc[NEXP];
#pragma unroll
  for (int e = 0; e < NEXP; e++) acc[e] = 0.f;
#pragma unroll
  for (int j = 0; j < 16; j++) {
    const float* wr = rw + (size_t)(d0 + j) * NEXP;
    float4 wa = *(const float4*)(wr);
    float4 wb = *(const float4*)(wr + 4);
    float xj = xv[j];
    acc[0] += xj * wa.x; acc[1] += xj * wa.y; acc[2] += xj * wa.z; acc[3] += xj * wa.w;
    acc[4] += xj * wb.x; acc[5] += xj * wb.y; acc[6] += xj * wb.z; acc[7] += xj * wb.w;
  }
#pragma unroll
  for (int off = 32; off > 0; off >>= 1)
#pragma unroll
    for (int e = 0; e < NEXP; e++) acc[e] += __shfl_xor(acc[e], off, 64);

  if (lane == 0) {
    int i0 = 0; float v0 = acc[0];
#pragma unroll
    for (int e = 1; e < NEXP; e++) if (acc[e] > v0) { v0 = acc[e]; i0 = e; }
    int i1 = (i0 == 0) ? 1 : 0; float v1 = acc[i1];
#pragma unroll
    for (int e = 0; e < NEXP; e++)
      if (e != i0 && acc[e] > v1) { v1 = acc[e]; i1 = e; }
    float p = __expf(v1 - v0);          // v1 <= v0
    float inv = 1.f / (1.f + p);
    top_idx[t] = i0 | (i1 << 16);
    top_w[t] = make_float2(inv, p * inv);
    atomicAdd(&counts[i0], 1);
    atomicAdd(&counts[i1], 1);
  }
}

// ------------------------------------------------------------------ scan ----
__global__ void scan_kernel(const int* __restrict__ counts,
                            int* __restrict__ offsets, int* __restrict__ cursor) {
  if (threadIdx.x == 0) {
    int s = 0;
    for (int e = 0; e < NEXP; e++) { offsets[e] = s; s += counts[e]; }
  }
  if (threadIdx.x < NEXP) cursor[threadIdx.x] = 0;
}

// ----------------------------------------------------------------- build ----
__global__ __launch_bounds__(256) void build_kernel(
    const int* __restrict__ top_idx, const float2* __restrict__ top_w,
    const int* __restrict__ offsets, int* cursor,
    int* __restrict__ list_token, float* __restrict__ list_w) {
  int t = blockIdx.x * 256 + threadIdx.x;
  if (t >= T_TOK) return;
  int pk = top_idx[t];
  float2 w = top_w[t];
  int e0 = pk & 0xffff, e1 = pk >> 16;
  int r0 = offsets[e0] + atomicAdd(&cursor[e0], 1);
  list_token[r0] = t; list_w[r0] = w.x;
  int r1 = offsets[e1] + atomicAdd(&cursor[e1], 1);
  list_token[r1] = t; list_w[r1] = w.y;
}

// ---------------------------------------------------- weight transpose ------
// src fp32 [mat][R][C] -> dst f16 [mat][C][R]   (B^T layout for the GEMMs)
__global__ __launch_bounds__(256) void transpose_cvt(
    const float* __restrict__ src, _Float16* __restrict__ dst, int R, int C) {
  __shared__ float tile[32][33];
  size_t mb = (size_t)blockIdx.z * R * C;
  src += mb; dst += mb;
  int c0 = blockIdx.x * 32, r0 = blockIdx.y * 32;
  int tx = threadIdx.x & 31, ty = threadIdx.x >> 5;   // ty: 0..7
#pragma unroll
  for (int j = 0; j < 4; j++)
    tile[ty + j * 8][tx] = src[(size_t)(r0 + ty + j * 8) * C + c0 + tx];
  __syncthreads();
#pragma unroll
  for (int j = 0; j < 4; j++)
    dst[(size_t)(c0 + ty + j * 8) * R + r0 + tx] = (_Float16)tile[tx][ty + j * 8];
}

// ----------------------------------------------------------------- GEMM1 ----
// per expert: h = silu(X Wg) * (X Wu), X gathered rows of xh.
// tile M=128 (tokens) x N=64 (hid) x BK=64. 4 waves, each 64x32 per matrix.
// LDS XOR swizzle: logical chunk c (8 halves) of row r stored at phys chunk c^(r&7).
__global__ __launch_bounds__(256) void gemm1_kernel(
    const _Float16* __restrict__ xh, const _Float16* __restrict__ wg_t,
    const _Float16* __restrict__ wu_t, const int* __restrict__ counts,
    const int* __restrict__ offsets, const int* __restrict__ list_token,
    _Float16* __restrict__ h) {
  int e = blockIdx.z;
  int Ne = counts[e];
  int m0 = blockIdx.y * 128;
  if (m0 >= Ne) return;
  int n0 = blockIdx.x * 64;
  int base = offsets[e];

  __shared__ _Float16 lds_a[128 * 64];
  __shared__ _Float16 lds_bg[64 * 64];
  __shared__ _Float16 lds_bu[64 * 64];

  int wave = threadIdx.x >> 6, lane = threadIdx.x & 63;
  int lsub = lane >> 3;                 // row within 8-row group
  int chunk = (lane & 7) ^ lsub;        // logical chunk this lane fetches

  const _Float16* ap[4];
#pragma unroll
  for (int j = 0; j < 4; j++) {
    int lr = j * 32 + wave * 8 + lsub;
    int gidx = base + m0 + lr;
    gidx = min(gidx, 2 * T_TOK - 1);                  // pad-row clamp
    int tok = list_token[gidx] & (T_TOK - 1);         // safety mask
    ap[j] = xh + (size_t)tok * EMB_D + chunk * 8;
  }
  const _Float16* bgp[2]; const _Float16* bup[2];
#pragma unroll
  for (int j = 0; j < 2; j++) {
    int nr = n0 + j * 32 + wave * 8 + lsub;
    bgp[j] = wg_t + ((size_t)e * HID_D + nr) * EMB_D + chunk * 8;
    bup[j] = wu_t + ((size_t)e * HID_D + nr) * EMB_D + chunk * 8;
  }

  f32x4 accg[4][2], accu[4][2];
#pragma unroll
  for (int im = 0; im < 4; im++)
#pragma unroll
    for (int in = 0; in < 2; in++) {
      accg[im][in] = (f32x4){0.f, 0.f, 0.f, 0.f};
      accu[im][in] = (f32x4){0.f, 0.f, 0.f, 0.f};
    }

  int wm = (wave >> 1) * 64, wn = (wave & 1) * 32;
  int frow = lane & 15, fquad = lane >> 4;

  for (int k0 = 0; k0 < EMB_D; k0 += 64) {
#pragma unroll
    for (int j = 0; j < 4; j++)
      GLD16(ap[j] + k0, lds_a + (j * 32 + wave * 8) * 64);
#pragma unroll
    for (int j = 0; j < 2; j++) {
      GLD16(bgp[j] + k0, lds_bg + (j * 32 + wave * 8) * 64);
      GLD16(bup[j] + k0, lds_bu + (j * 32 + wave * 8) * 64);
    }
    __syncthreads();
#pragma unroll
    for (int ks = 0; ks < 64; ks += 32) {
      int c = (ks >> 3) + fquad;                 // logical chunk
      int sw = ((c ^ (frow & 7)) << 3);          // swizzled element offset
      f16x8 af[4], bgf[2], buf[2];
#pragma unroll
      for (int im = 0; im < 4; im++)
        af[im] = *(const f16x8*)(lds_a + (wm + im * 16 + frow) * 64 + sw);
#pragma unroll
      for (int in = 0; in < 2; in++) {
        bgf[in] = *(const f16x8*)(lds_bg + (wn + in * 16 + frow) * 64 + sw);
        buf[in] = *(const f16x8*)(lds_bu + (wn + in * 16 + frow) * 64 + sw);
      }
#pragma unroll
      for (int im = 0; im < 4; im++)
#pragma unroll
        for (int in = 0; in < 2; in++) {
          accg[im][in] = __builtin_amdgcn_mfma_f32_16x16x32_f16(
              af[im], bgf[in], accg[im][in], 0, 0, 0);
          accu[im][in] = __builtin_amdgcn_mfma_f32_16x16x32_f16(
              af[im], buf[in], accu[im][in], 0, 0, 0);
        }
    }
    __syncthreads();
  }

#pragma unroll
  for (int im = 0; im < 4; im++)
#pragma unroll
    for (int in = 0; in < 2; in++)
#pragma unroll
      for (int r = 0; r < 4; r++) {
        int lm = m0 + wm + im * 16 + fquad * 4 + r;
        if (lm < Ne) {
          int col = n0 + wn + in * 16 + frow;
          float g = accg[im][in][r], u = accu[im][in][r];
          float hv = (g / (1.f + __expf(-g))) * u;    // silu(g)*u
          h[(size_t)(base + lm) * HID_D + col] = (_Float16)hv;
        }
      }
}

// ----------------------------------------------------------------- GEMM2 ----
// out[tok] += w * (h_row @ Wd).  tile 128x128, BK=64.
__global__ __launch_bounds__(256) void gemm2_kernel(
    const _Float16* __restrict__ h, const _Float16* __restrict__ wd_t,
    const int* __restrict__ counts, const int* __restrict__ offsets,
    const int* __restrict__ list_token, const float* __restrict__ list_w,
    float* __restrict__ out) {
  int e = blockIdx.z;
  int Ne = counts[e];
  int m0 = blockIdx.y * 128;
  if (m0 >= Ne) return;
  int n0 = blockIdx.x * 128;
  int base = offsets[e];

  __shared__ _Float16 lds_a[128 * 64];
  __shared__ _Float16 lds_b[128 * 64];

  int wave = threadIdx.x >> 6, lane = threadIdx.x & 63;
  int lsub = lane >> 3;
  int chunk = (lane & 7) ^ lsub;

  const _Float16* ap[4]; const _Float16* bp[4];
#pragma unroll
  for (int j = 0; j < 4; j++) {
    int lr = j * 32 + wave * 8 + lsub;
    ap[j] = h + (size_t)(base + m0 + lr) * HID_D + chunk * 8;   // LIST_CAP slack covers pad
    bp[j] = wd_t + ((size_t)e * EMB_D + n0 + lr) * HID_D + chunk * 8;
  }

  f32x4 acc[4][4];
#pragma unroll
  for (int im = 0; im < 4; im++)
#pragma unroll
    for (int in = 0; in < 4; in++) acc[im][in] = (f32x4){0.f, 0.f, 0.f, 0.f};

  int wm = (wave >> 1) * 64, wn = (wave & 1) * 64;
  int frow = lane & 15, fquad = lane >> 4;

  for (int k0 = 0; k0 < HID_D; k0 += 64) {
#pragma unroll
    for (int j = 0; j < 4; j++) GLD16(ap[j] + k0, lds_a + (j * 32 + wave * 8) * 64);
#pragma unroll
    for (int j = 0; j < 4; j++) GLD16(bp[j] + k0, lds_b + (j * 32 + wave * 8) * 64);
    __syncthreads();
#pragma unroll
    for (int ks = 0; ks < 64; ks += 32) {
      int c = (ks >> 3) + fquad;
      int sw = ((c ^ (frow & 7)) << 3);
      f16x8 af[4], bf[4];
#pragma unroll
      for (int im = 0; im < 4; im++)
        af[im] = *(const f16x8*)(lds_a + (wm + im * 16 + frow) * 64 + sw);
#pragma unroll
      for (int in = 0; in < 4; in++)
        bf[in] = *(const f16x8*)(lds_b + (wn + in * 16 + frow) * 64 + sw);
#pragma unroll
      for (int im = 0; im < 4; im++)
#pragma unroll
        for (int in = 0; in < 4; in++)
          acc[im][in] = __builtin_amdgcn_mfma_f32_16x16x32_f16(
              af[im], bf[in], acc[im][in], 0, 0, 0);
    }
    __syncthreads();
  }

#pragma unroll
  for (int im = 0; im < 4; im++)
#pragma unroll
    for (int r = 0; r < 4; r++) {
      int lm = m0 + wm + im * 16 + fquad * 4 + r;
      if (lm < Ne) {
        int gi = base + lm;
        int tok = list_token[gi];
        float w = list_w[gi];
#pragma unroll
        for (int in = 0; in < 4; in++) {
          int col = n0 + wn + in * 16 + frow;
          atomicAdd(out + (size_t)tok * EMB_D + col, acc[im][in][r] * w);
        }
      }
    }
}

// ---------------------------------------------------------------- launch ----
extern "C" void kernel_launch(void* const* d_in, const int* in_sizes, int n_in,
                              void* d_out, int out_size, void* d_ws, size_t ws_size,
                              hipStream_t stream) {
  const float* x  = (const float*)d_in[0];
  const float* rw = (const float*)d_in[1];
  const float* wg = (const float*)d_in[2];
  const float* wu = (const float*)d_in[3];
  const float* wd = (const float*)d_in[4];
  float* out = (float*)d_out;

  char* ws = (char*)d_ws;
  size_t off = 0;
  auto alloc = [&](size_t bytes) -> void* {
    void* p = ws + off;
    off += (bytes + 255) & ~(size_t)255;
    return p;
  };
  int*    counts     = (int*)alloc(NEXP * 4);
  int*    cursor     = (int*)alloc(NEXP * 4);
  int*    offsets    = (int*)alloc(NEXP * 4);
  int*    top_idx    = (int*)alloc((size_t)T_TOK * 4);
  float2* top_w      = (float2*)alloc((size_t)T_TOK * 8);
  int*    list_token = (int*)alloc((size_t)LIST_CAP * 4);
  float*  list_w     = (float*)alloc((size_t)LIST_CAP * 4);
  _Float16* xh   = (_Float16*)alloc((size_t)T_TOK * EMB_D * 2);
  _Float16* wg_t = (_Float16*)alloc((size_t)NEXP * HID_D * EMB_D * 2);
  _Float16* wu_t = (_Float16*)alloc((size_t)NEXP * HID_D * EMB_D * 2);
  _Float16* wd_t = (_Float16*)alloc((size_t)NEXP * EMB_D * HID_D * 2);
  _Float16* h    = (_Float16*)alloc((size_t)LIST_CAP * HID_D * 2);

  hipMemsetAsync(counts, 0, NEXP * 4, stream);
  hipMemsetAsync(out, 0, (size_t)out_size * sizeof(float), stream);

  router_kernel<<<T_TOK / 4, 256, 0, stream>>>(x, rw, xh, top_idx, top_w, counts);
  transpose_cvt<<<dim3(HID_D / 32, EMB_D / 32, NEXP), 256, 0, stream>>>(wg, wg_t, EMB_D, HID_D);
  transpose_cvt<<<dim3(HID_D / 32, EMB_D / 32, NEXP), 256, 0, stream>>>(wu, wu_t, EMB_D, HID_D);
  transpose_cvt<<<dim3(EMB_D / 32, HID_D / 32, NEXP), 256, 0, stream>>>(wd, wd_t, HID_D, EMB_D);
  scan_kernel<<<1, 64, 0, stream>>>(counts, offsets, cursor);
  build_kernel<<<T_TOK / 256, 256, 0, stream>>>(top_idx, top_w, offsets, cursor,
                                                list_token, list_w);
  gemm1_kernel<<<dim3(HID_D / 64, T_TOK / 128, NEXP), 256, 0, stream>>>(
      xh, wg_t, wu_t, counts, offsets, list_token, h);
  gemm2_kernel<<<dim3(EMB_D / 128, T_TOK / 128, NEXP), 256, 0, stream>>>(
      h, wd_t, counts, offsets, list_token, list_w, out);
}

// Round 2
// 1403.009 us; speedup vs baseline: 1.0400x; 1.0400x over previous
//
#include <hip/hip_runtime.h>
#include <hip/hip_fp16.h>

// MoE top-2, T=16384 tokens, D=1024, H=2048, E=8. All inputs fp32.
// Pipeline: router(top2+x->f16) -> scan -> build lists (+inverse map) ->
// transpose-cvt weights -> grouped GEMM1 (gate+up fused, SiLU) ->
// grouped GEMM2 (down, scaled f16 row store) -> combine (out = y[r0]+y[r1]).
// Internal compute f16 MFMA (16x16x32), fp32 accumulate. Router kept fp32.
// R1->R2: replaced gemm2's 33.5M fp32 atomicAdds with scaled f16 row stores
// + a streaming combine kernel; y aliased onto dead xh/wg_t/wu_t region.

#define T_TOK 16384
#define EMB_D 1024
#define HID_D 2048
#define NEXP  8
#define LIST_CAP (2 * T_TOK + 256)

typedef _Float16 f16x8 __attribute__((ext_vector_type(8)));
typedef float    f32x4 __attribute__((ext_vector_type(4)));

// async global->LDS, 16B per lane, lane i lands at ldsbase + i*16B
#define GLD16(gp, lp)                                                          \
  __builtin_amdgcn_global_load_lds(                                            \
      (__attribute__((address_space(1))) void*)(void*)(gp),                    \
      (__attribute__((address_space(3))) void*)(lp), 16, 0, 0)

// ---------------------------------------------------------------- router ----
__global__ __launch_bounds__(256) void router_kernel(
    const float* __restrict__ x, const float* __restrict__ rw,
    _Float16* __restrict__ xh, int* __restrict__ top_idx,
    float2* __restrict__ top_w, int* __restrict__ counts) {
  int wave = threadIdx.x >> 6, lane = threadIdx.x & 63;
  int t = blockIdx.x * 4 + wave;              // one wave per token
  const float* xr = x + (size_t)t * EMB_D;
  int d0 = lane * 16;

  float xv[16];
#pragma unroll
  for (int j = 0; j < 4; j++) {
    float4 v = *(const float4*)(xr + d0 + j * 4);
    xv[j * 4 + 0] = v.x; xv[j * 4 + 1] = v.y;
    xv[j * 4 + 2] = v.z; xv[j * 4 + 3] = v.w;
  }
  // fused fp32 -> f16 conversion of x
  _Float16 hx[16];
#pragma unroll
  for (int j = 0; j < 16; j++) hx[j] = (_Float16)xv[j];
  *(f16x8*)(xh + (size_t)t * EMB_D + d0)     = *(f16x8*)(hx);
  *(f16x8*)(xh + (size_t)t * EMB_D + d0 + 8) = *(f16x8*)(hx + 8);

  // logits in fp32 (selection must be exact-ish)
  float acc[NEXP];
#pragma unroll
  for (int e = 0; e < NEXP; e++) acc[e] = 0.f;
#pragma unroll
  for (int j = 0; j < 16; j++) {
    const float* wr = rw + (size_t)(d0 + j) * NEXP;
    float4 wa = *(const float4*)(wr);
    float4 wb = *(const float4*)(wr + 4);
    float xj = xv[j];
    acc[0] += xj * wa.x; acc[1] += xj * wa.y; acc[2] += xj * wa.z; acc[3] += xj * wa.w;
    acc[4] += xj * wb.x; acc[5] += xj * wb.y; acc[6] += xj * wb.z; acc[7] += xj * wb.w;
  }
#pragma unroll
  for (int off = 32; off > 0; off >>= 1)
#pragma unroll
    for (int e = 0; e < NEXP; e++) acc[e] += __shfl_xor(acc[e], off, 64);

  if (lane == 0) {
    int i0 = 0; float v0 = acc[0];
#pragma unroll
    for (int e = 1; e < NEXP; e++) if (acc[e] > v0) { v0 = acc[e]; i0 = e; }
    int i1 = (i0 == 0) ? 1 : 0; float v1 = acc[i1];
#pragma unroll
    for (int e = 0; e < NEXP; e++)
      if (e != i0 && acc[e] > v1) { v1 = acc[e]; i1 = e; }
    float p = __expf(v1 - v0);          // v1 <= v0
    float inv = 1.f / (1.f + p);
    top_idx[t] = i0 | (i1 << 16);
    top_w[t] = make_float2(inv, p * inv);
    atomicAdd(&counts[i0], 1);
    atomicAdd(&counts[i1], 1);
  }
}

// ------------------------------------------------------------------ scan ----
__global__ void scan_kernel(const int* __restrict__ counts,
                            int* __restrict__ offsets, int* __restrict__ cursor) {
  if (threadIdx.x == 0) {
    int s = 0;
    for (int e = 0; e < NEXP; e++) { offsets[e] = s; s += counts[e]; }
  }
  if (threadIdx.x < NEXP) cursor[threadIdx.x] = 0;
}

// ----------------------------------------------------------------- build ----
__global__ __launch_bounds__(256) void build_kernel(
    const int* __restrict__ top_idx, const float2* __restrict__ top_w,
    const int* __restrict__ offsets, int* cursor,
    int* __restrict__ list_token, float* __restrict__ list_w,
    int2* __restrict__ rows) {
  int t = blockIdx.x * 256 + threadIdx.x;
  if (t >= T_TOK) return;
  int pk = top_idx[t];
  float2 w = top_w[t];
  int e0 = pk & 0xffff, e1 = pk >> 16;
  int r0 = offsets[e0] + atomicAdd(&cursor[e0], 1);
  list_token[r0] = t; list_w[r0] = w.x;
  int r1 = offsets[e1] + atomicAdd(&cursor[e1], 1);
  list_token[r1] = t; list_w[r1] = w.y;
  rows[t] = make_int2(r0, r1);
}

// ---------------------------------------------------- weight transpose ------
// src fp32 [mat][R][C] -> dst f16 [mat][C][R]   (B^T layout for the GEMMs)
__global__ __launch_bounds__(256) void transpose_cvt(
    const float* __restrict__ src, _Float16* __restrict__ dst, int R, int C) {
  __shared__ float tile[32][33];
  size_t mb = (size_t)blockIdx.z * R * C;
  src += mb; dst += mb;
  int c0 = blockIdx.x * 32, r0 = blockIdx.y * 32;
  int tx = threadIdx.x & 31, ty = threadIdx.x >> 5;   // ty: 0..7
#pragma unroll
  for (int j = 0; j < 4; j++)
    tile[ty + j * 8][tx] = src[(size_t)(r0 + ty + j * 8) * C + c0 + tx];
  __syncthreads();
#pragma unroll
  for (int j = 0; j < 4; j++)
    dst[(size_t)(c0 + ty + j * 8) * R + r0 + tx] = (_Float16)tile[tx][ty + j * 8];
}

// ----------------------------------------------------------------- GEMM1 ----
// per expert: h = silu(X Wg) * (X Wu), X gathered rows of xh.
// tile M=128 (tokens) x N=64 (hid) x BK=64. 4 waves, each 64x32 per matrix.
// LDS XOR swizzle: logical chunk c (8 halves) of row r stored at phys chunk c^(r&7).
__global__ __launch_bounds__(256) void gemm1_kernel(
    const _Float16* __restrict__ xh, const _Float16* __restrict__ wg_t,
    const _Float16* __restrict__ wu_t, const int* __restrict__ counts,
    const int* __restrict__ offsets, const int* __restrict__ list_token,
    _Float16* __restrict__ h) {
  int e = blockIdx.z;
  int Ne = counts[e];
  int m0 = blockIdx.y * 128;
  if (m0 >= Ne) return;
  int n0 = blockIdx.x * 64;
  int base = offsets[e];

  __shared__ _Float16 lds_a[128 * 64];
  __shared__ _Float16 lds_bg[64 * 64];
  __shared__ _Float16 lds_bu[64 * 64];

  int wave = threadIdx.x >> 6, lane = threadIdx.x & 63;
  int lsub = lane >> 3;                 // row within 8-row group
  int chunk = (lane & 7) ^ lsub;        // logical chunk this lane fetches

  const _Float16* ap[4];
#pragma unroll
  for (int j = 0; j < 4; j++) {
    int lr = j * 32 + wave * 8 + lsub;
    int gidx = base + m0 + lr;
    gidx = min(gidx, 2 * T_TOK - 1);                  // pad-row clamp
    int tok = list_token[gidx] & (T_TOK - 1);         // safety mask
    ap[j] = xh + (size_t)tok * EMB_D + chunk * 8;
  }
  const _Float16* bgp[2]; const _Float16* bup[2];
#pragma unroll
  for (int j = 0; j < 2; j++) {
    int nr = n0 + j * 32 + wave * 8 + lsub;
    bgp[j] = wg_t + ((size_t)e * HID_D + nr) * EMB_D + chunk * 8;
    bup[j] = wu_t + ((size_t)e * HID_D + nr) * EMB_D + chunk * 8;
  }

  f32x4 accg[4][2], accu[4][2];
#pragma unroll
  for (int im = 0; im < 4; im++)
#pragma unroll
    for (int in = 0; in < 2; in++) {
      accg[im][in] = (f32x4){0.f, 0.f, 0.f, 0.f};
      accu[im][in] = (f32x4){0.f, 0.f, 0.f, 0.f};
    }

  int wm = (wave >> 1) * 64, wn = (wave & 1) * 32;
  int frow = lane & 15, fquad = lane >> 4;

  for (int k0 = 0; k0 < EMB_D; k0 += 64) {
#pragma unroll
    for (int j = 0; j < 4; j++)
      GLD16(ap[j] + k0, lds_a + (j * 32 + wave * 8) * 64);
#pragma unroll
    for (int j = 0; j < 2; j++) {
      GLD16(bgp[j] + k0, lds_bg + (j * 32 + wave * 8) * 64);
      GLD16(bup[j] + k0, lds_bu + (j * 32 + wave * 8) * 64);
    }
    __syncthreads();
#pragma unroll
    for (int ks = 0; ks < 64; ks += 32) {
      int c = (ks >> 3) + fquad;                 // logical chunk
      int sw = ((c ^ (frow & 7)) << 3);          // swizzled element offset
      f16x8 af[4], bgf[2], buf[2];
#pragma unroll
      for (int im = 0; im < 4; im++)
        af[im] = *(const f16x8*)(lds_a + (wm + im * 16 + frow) * 64 + sw);
#pragma unroll
      for (int in = 0; in < 2; in++) {
        bgf[in] = *(const f16x8*)(lds_bg + (wn + in * 16 + frow) * 64 + sw);
        buf[in] = *(const f16x8*)(lds_bu + (wn + in * 16 + frow) * 64 + sw);
      }
#pragma unroll
      for (int im = 0; im < 4; im++)
#pragma unroll
        for (int in = 0; in < 2; in++) {
          accg[im][in] = __builtin_amdgcn_mfma_f32_16x16x32_f16(
              af[im], bgf[in], accg[im][in], 0, 0, 0);
          accu[im][in] = __builtin_amdgcn_mfma_f32_16x16x32_f16(
              af[im], buf[in], accu[im][in], 0, 0, 0);
        }
    }
    __syncthreads();
  }

#pragma unroll
  for (int im = 0; im < 4; im++)
#pragma unroll
    for (int in = 0; in < 2; in++)
#pragma unroll
      for (int r = 0; r < 4; r++) {
        int lm = m0 + wm + im * 16 + fquad * 4 + r;
        if (lm < Ne) {
          int col = n0 + wn + in * 16 + frow;
          float g = accg[im][in][r], u = accu[im][in][r];
          float hv = (g / (1.f + __expf(-g))) * u;    // silu(g)*u
          h[(size_t)(base + lm) * HID_D + col] = (_Float16)hv;
        }
      }
}

// ----------------------------------------------------------------- GEMM2 ----
// y[list_row] = w * (h_row @ Wd)  (f16 store; no atomics).  tile 128x128, BK=64.
__global__ __launch_bounds__(256) void gemm2_kernel(
    const _Float16* __restrict__ h, const _Float16* __restrict__ wd_t,
    const int* __restrict__ counts, const int* __restrict__ offsets,
    const float* __restrict__ list_w, _Float16* __restrict__ y) {
  int e = blockIdx.z;
  int Ne = counts[e];
  int m0 = blockIdx.y * 128;
  if (m0 >= Ne) return;
  int n0 = blockIdx.x * 128;
  int base = offsets[e];

  __shared__ _Float16 lds_a[128 * 64];
  __shared__ _Float16 lds_b[128 * 64];

  int wave = threadIdx.x >> 6, lane = threadIdx.x & 63;
  int lsub = lane >> 3;
  int chunk = (lane & 7) ^ lsub;

  const _Float16* ap[4]; const _Float16* bp[4];
#pragma unroll
  for (int j = 0; j < 4; j++) {
    int lr = j * 32 + wave * 8 + lsub;
    ap[j] = h + (size_t)(base + m0 + lr) * HID_D + chunk * 8;   // LIST_CAP slack covers pad
    bp[j] = wd_t + ((size_t)e * EMB_D + n0 + lr) * HID_D + chunk * 8;
  }

  f32x4 acc[4][4];
#pragma unroll
  for (int im = 0; im < 4; im++)
#pragma unroll
    for (int in = 0; in < 4; in++) acc[im][in] = (f32x4){0.f, 0.f, 0.f, 0.f};

  int wm = (wave >> 1) * 64, wn = (wave & 1) * 64;
  int frow = lane & 15, fquad = lane >> 4;

  for (int k0 = 0; k0 < HID_D; k0 += 64) {
#pragma unroll
    for (int j = 0; j < 4; j++) GLD16(ap[j] + k0, lds_a + (j * 32 + wave * 8) * 64);
#pragma unroll
    for (int j = 0; j < 4; j++) GLD16(bp[j] + k0, lds_b + (j * 32 + wave * 8) * 64);
    __syncthreads();
#pragma unroll
    for (int ks = 0; ks < 64; ks += 32) {
      int c = (ks >> 3) + fquad;
      int sw = ((c ^ (frow & 7)) << 3);
      f16x8 af[4], bf[4];
#pragma unroll
      for (int im = 0; im < 4; im++)
        af[im] = *(const f16x8*)(lds_a + (wm + im * 16 + frow) * 64 + sw);
#pragma unroll
      for (int in = 0; in < 4; in++)
        bf[in] = *(const f16x8*)(lds_b + (wn + in * 16 + frow) * 64 + sw);
#pragma unroll
      for (int im = 0; im < 4; im++)
#pragma unroll
        for (int in = 0; in < 4; in++)
          acc[im][in] = __builtin_amdgcn_mfma_f32_16x16x32_f16(
              af[im], bf[in], acc[im][in], 0, 0, 0);
    }
    __syncthreads();
  }

#pragma unroll
  for (int im = 0; im < 4; im++)
#pragma unroll
    for (int r = 0; r < 4; r++) {
      int lm = m0 + wm + im * 16 + fquad * 4 + r;
      if (lm < Ne) {
        int gi = base + lm;
        float w = list_w[gi];
#pragma unroll
        for (int in = 0; in < 4; in++) {
          int col = n0 + wn + in * 16 + frow;
          y[(size_t)gi * EMB_D + col] = (_Float16)(acc[im][in][r] * w);
        }
      }
    }
}

// --------------------------------------------------------------- combine ----
// out[t] = y[r0(t)] + y[r1(t)]   (fp32 out; y rows already weight-scaled)
__global__ __launch_bounds__(256) void combine_kernel(
    const _Float16* __restrict__ y, const int2* __restrict__ rows,
    float* __restrict__ out) {
  int tid = blockIdx.x * 256 + threadIdx.x;   // T*128 threads, 8 elems each
  int t = tid >> 7;
  int d0 = (tid & 127) * 8;
  int2 r = rows[t];
  f16x8 a = *(const f16x8*)(y + (size_t)r.x * EMB_D + d0);
  f16x8 b = *(const f16x8*)(y + (size_t)r.y * EMB_D + d0);
  float o[8];
#pragma unroll
  for (int j = 0; j < 8; j++) o[j] = (float)a[j] + (float)b[j];
  float* op = out + (size_t)t * EMB_D + d0;
  *(float4*)(op)     = make_float4(o[0], o[1], o[2], o[3]);
  *(float4*)(op + 4) = make_float4(o[4], o[5], o[6], o[7]);
}

// ---------------------------------------------------------------- launch ----
extern "C" void kernel_launch(void* const* d_in, const int* in_sizes, int n_in,
                              void* d_out, int out_size, void* d_ws, size_t ws_size,
                              hipStream_t stream) {
  const float* x  = (const float*)d_in[0];
  const float* rw = (const float*)d_in[1];
  const float* wg = (const float*)d_in[2];
  const float* wu = (const float*)d_in[3];
  const float* wd = (const float*)d_in[4];
  float* out = (float*)d_out;

  char* ws = (char*)d_ws;
  size_t off = 0;
  auto alloc = [&](size_t bytes) -> void* {
    void* p = ws + off;
    off += (bytes + 255) & ~(size_t)255;
    return p;
  };
  int*    counts     = (int*)alloc(NEXP * 4);
  int*    cursor     = (int*)alloc(NEXP * 4);
  int*    offsets    = (int*)alloc(NEXP * 4);
  int*    top_idx    = (int*)alloc((size_t)T_TOK * 4);
  float2* top_w      = (float2*)alloc((size_t)T_TOK * 8);
  int*    list_token = (int*)alloc((size_t)LIST_CAP * 4);
  float*  list_w     = (float*)alloc((size_t)LIST_CAP * 4);
  int2*   rows       = (int2*)alloc((size_t)T_TOK * 8);
  _Float16* xh   = (_Float16*)alloc((size_t)T_TOK * EMB_D * 2);
  _Float16* wg_t = (_Float16*)alloc((size_t)NEXP * HID_D * EMB_D * 2);
  _Float16* wu_t = (_Float16*)alloc((size_t)NEXP * HID_D * EMB_D * 2);
  _Float16* wd_t = (_Float16*)alloc((size_t)NEXP * EMB_D * HID_D * 2);
  _Float16* h    = (_Float16*)alloc((size_t)LIST_CAP * HID_D * 2);
  // y aliased onto xh+wg_t+wu_t (dead after gemm1): needs LIST_CAP*EMB_D*2
  // = 68.2 MB; region is 100.7 MB. gemm2 reads only h/wd_t/list_w.
  _Float16* y = xh;

  hipMemsetAsync(counts, 0, NEXP * 4, stream);

  router_kernel<<<T_TOK / 4, 256, 0, stream>>>(x, rw, xh, top_idx, top_w, counts);
  transpose_cvt<<<dim3(HID_D / 32, EMB_D / 32, NEXP), 256, 0, stream>>>(wg, wg_t, EMB_D, HID_D);
  transpose_cvt<<<dim3(HID_D / 32, EMB_D / 32, NEXP), 256, 0, stream>>>(wu, wu_t, EMB_D, HID_D);
  transpose_cvt<<<dim3(EMB_D / 32, HID_D / 32, NEXP), 256, 0, stream>>>(wd, wd_t, HID_D, EMB_D);
  scan_kernel<<<1, 64, 0, stream>>>(counts, offsets, cursor);
  build_kernel<<<T_TOK / 256, 256, 0, stream>>>(top_idx, top_w, offsets, cursor,
                                                list_token, list_w, rows);
  gemm1_kernel<<<dim3(HID_D / 64, T_TOK / 128, NEXP), 256, 0, stream>>>(
      xh, wg_t, wu_t, counts, offsets, list_token, h);
  gemm2_kernel<<<dim3(EMB_D / 128, T_TOK / 128, NEXP), 256, 0, stream>>>(
      h, wd_t, counts, offsets, list_w, y);
  combine_kernel<<<T_TOK * 128 / 256, 256, 0, stream>>>(y, rows, out);
}